// Round 9
// baseline (222.067 us; speedup 1.0000x reference)
//
#include <hip/hip_runtime.h>
#include <hip/hip_bf16.h>
#include <math.h>

#define BB 2
#define SS 4096
#define DD 512
#define HH 8
#define HD 64
#define MSD (BB*SS*DD)          // 4194304 elements per matrix
#define WSZ (DD*DD)             // 262144 elements per weight

// ws layout (ushort elements):
//   Qb @ 0      [bh][s][hd]  (pre-scaled by log2e/sqrt(512))
//   Kb @ MSD    [bh][s][hd]
//   Vt @ 2*MSD  [bh][hd][s]
//   xb @ 4*MSD  [m][k]
//   Wb @ 5*MSD  3 x [n][k]
#define XOFF (4*(size_t)MSD)
#define WOFF (5*(size_t)MSD)

typedef __attribute__((ext_vector_type(8))) short bf16x8;
typedef __attribute__((ext_vector_type(4))) float f32x4;

__device__ __forceinline__ unsigned short f2bf(float f) {
    unsigned int u = __float_as_uint(f);
    u += 0x7fff + ((u >> 16) & 1);
    return (unsigned short)(u >> 16);
}
__device__ __forceinline__ unsigned int pk2bf(float a, float b) {
    __hip_bfloat162 h = __float22bfloat162_rn(make_float2(a, b));
    union { __hip_bfloat162 h2; unsigned int u; } cv; cv.h2 = h;
    return cv.u;   // low 16 = a, high 16 = b
}

#define GLD16(gsrc, ldst) \
    __builtin_amdgcn_global_load_lds((const __attribute__((address_space(1))) unsigned int*)(gsrc), \
                                     (__attribute__((address_space(3))) unsigned int*)(ldst), 16, 0, 0)

// ---------------------------------------------------------------------------
// fp32 -> bf16 convert: x (MSD els) and Wq|Wk|Wv (3*WSZ els). 8 els/thread.
// ---------------------------------------------------------------------------
__global__ __launch_bounds__(256)
void convert_bf16(const float* __restrict__ x,
                  const float* __restrict__ Wq, const float* __restrict__ Wk,
                  const float* __restrict__ Wv, unsigned short* __restrict__ ws) {
    const int i8 = blockIdx.x*256 + threadIdx.x;
    const float* src; unsigned short* dst; size_t off;
    if (i8 < MSD/8) {
        src = x; dst = ws + XOFF; off = (size_t)i8 * 8;
    } else {
        size_t o = ((size_t)i8 - MSD/8) * 8;
        int wsel = (int)(o / WSZ);
        src = (wsel == 0) ? Wq : (wsel == 1) ? Wk : Wv;
        dst = ws + WOFF + (size_t)wsel*WSZ;
        off = o % WSZ;
    }
    float4 a = *(const float4*)&src[off];
    float4 b = *(const float4*)&src[off+4];
    unsigned short r[8] = { f2bf(a.x), f2bf(a.y), f2bf(a.z), f2bf(a.w),
                            f2bf(b.x), f2bf(b.y), f2bf(b.z), f2bf(b.w) };
    *(bf16x8*)&dst[off] = *(const bf16x8*)r;
}

// ---------------------------------------------------------------------------
// QKV GEMM, bf16 MFMA: C = X @ W^T + b. 128x128 tile, BK=64, 4 waves (2x2).
// z<2: operand-swapped MFMA -> C^T regs; z=2: natural -> C regs.
// Epilogue: C round-trips through LDS (XOR-swizzled), then COALESCED stores.
// grid (4, 64, 3), block 256.
// ---------------------------------------------------------------------------
__global__ __launch_bounds__(256)
void qkv_mfma(const float* __restrict__ bq, const float* __restrict__ bk,
              const float* __restrict__ bv, unsigned short* __restrict__ ws) {
    const int z = blockIdx.z;
    const unsigned short* Xb = ws + XOFF;
    const unsigned short* Wb = ws + WOFF + (size_t)z*WSZ;
    const float* bias = (z == 0) ? bq : (z == 1) ? bk : bv;
    unsigned short* dst = ws + (size_t)z*MSD;

    __shared__ __align__(16) unsigned short Sh[2*128*64];   // As | Bs, reused as C-tile
    unsigned short* As = Sh;
    unsigned short* Bs = Sh + 128*64;

    const int tid  = threadIdx.x;
    const int w    = tid >> 6, l = tid & 63;
    const int quad = l >> 4,  r16 = l & 15;
    const int wy   = w >> 1,  wx  = w & 1;
    const int m0   = blockIdx.y * 128;
    const int n0   = blockIdx.x * 128;

    const int srow   = l >> 3;
    const int schunk = (l & 7) ^ srow;

    f32x4 acc[4][4];
    #pragma unroll
    for (int i = 0; i < 4; ++i)
        #pragma unroll
        for (int j = 0; j < 4; ++j) acc[i][j] = (f32x4){0.f,0.f,0.f,0.f};

    for (int k0 = 0; k0 < DD; k0 += 64) {
        __syncthreads();
        #pragma unroll
        for (int u = 0; u < 4; ++u) {
            const int r0 = w*32 + u*8;
            GLD16(&Xb[(size_t)(m0 + r0 + srow)*DD + k0 + schunk*8], &As[r0*64]);
            GLD16(&Wb[(size_t)(n0 + r0 + srow)*DD + k0 + schunk*8], &Bs[r0*64]);
        }
        __syncthreads();
        #pragma unroll
        for (int kc = 0; kc < 2; ++kc) {
            bf16x8 a[4], b[4];
            #pragma unroll
            for (int i = 0; i < 4; ++i) {
                const int mr = wy*64 + i*16 + r16;
                a[i] = *(const bf16x8*)&As[mr*64 + (((kc*4+quad) ^ (mr&7))*8)];
                const int nr = wx*64 + i*16 + r16;
                b[i] = *(const bf16x8*)&Bs[nr*64 + (((kc*4+quad) ^ (nr&7))*8)];
            }
            #pragma unroll
            for (int i = 0; i < 4; ++i)
                #pragma unroll
                for (int j = 0; j < 4; ++j) {
                    if (z == 2)
                        acc[i][j] = __builtin_amdgcn_mfma_f32_16x16x32_bf16(a[i], b[j], acc[i][j], 0, 0, 0);
                    else
                        acc[i][j] = __builtin_amdgcn_mfma_f32_16x16x32_bf16(b[j], a[i], acc[i][j], 0, 0, 0);
                }
        }
    }

    __syncthreads();   // k-loop LDS reads done; reuse Sh as 128x128 C-tile

    const float qscale = 0.04419417382415922f * 1.4426950408889634f; // 1/sqrt(512)*log2e
    if (z == 2) {
        #pragma unroll
        for (int j = 0; j < 4; ++j) {
            const int nloc = wx*64 + j*16 + r16;
            const float bz = bias[n0 + nloc];
            #pragma unroll
            for (int i = 0; i < 4; ++i) {
                const int chunk = wy*8 + i*2 + (quad>>1);
                const int off   = (quad & 1) * 4;
                unsigned short r4[4];
                #pragma unroll
                for (int reg = 0; reg < 4; ++reg)
                    r4[reg] = f2bf(acc[i][j][reg] + bz);
                *(uint2*)&Sh[nloc*128 + ((chunk ^ (nloc & 7))*8) + off] = *(const uint2*)r4;
            }
        }
    } else {
        #pragma unroll
        for (int j = 0; j < 4; ++j) {
            const int nbase = wx*64 + j*16 + quad*4;
            const float4 bz4 = *(const float4*)&bias[n0 + nbase];
            const int chunk = wx*8 + j*2 + (quad>>1);
            const int off   = (quad & 1) * 4;
            #pragma unroll
            for (int i = 0; i < 4; ++i) {
                const int mloc = wy*64 + i*16 + r16;
                float v0 = acc[i][j][0] + bz4.x;
                float v1 = acc[i][j][1] + bz4.y;
                float v2 = acc[i][j][2] + bz4.z;
                float v3 = acc[i][j][3] + bz4.w;
                if (z == 0) { v0 *= qscale; v1 *= qscale; v2 *= qscale; v3 *= qscale; }
                unsigned short r4[4] = { f2bf(v0), f2bf(v1), f2bf(v2), f2bf(v3) };
                *(uint2*)&Sh[mloc*128 + ((chunk ^ (mloc & 7))*8) + off] = *(const uint2*)r4;
            }
        }
    }
    __syncthreads();

    if (z == 2) {
        const int b_ = m0 >> 12, s0_ = m0 & (SS-1);
        #pragma unroll
        for (int p = 0; p < 8; ++p) {
            const int f = p*256 + tid;
            const int nrow = f >> 4;
            const int mch  = f & 15;
            bf16x8 v = *(const bf16x8*)&Sh[nrow*128 + ((mch ^ (nrow & 7))*8)];
            const int ng = n0 + nrow;
            const int h = ng >> 6, hd = ng & 63;
            *(bf16x8*)&dst[((size_t)(b_*HH + h)*HD + hd)*SS + s0_ + mch*8] = v;
        }
    } else {
        #pragma unroll
        for (int p = 0; p < 8; ++p) {
            const int f = p*256 + tid;
            const int hh  = f >> 10;
            const int rem = f & 1023;
            const int sr  = rem >> 3;
            const int ch  = rem & 7;
            bf16x8 v = *(const bf16x8*)&Sh[sr*128 + (((hh*8 + ch) ^ (sr & 7))*8)];
            const int mg = m0 + sr;
            const int b_ = mg >> 12, s_ = mg & (SS-1);
            const int hg = (n0 >> 6) + hh;
            *(bf16x8*)&dst[((size_t)(b_*HH + hg)*SS + s_)*HD + ch*8] = v;
        }
    }
}

// ---------------------------------------------------------------------------
// MFMA flash attention, DMA double-buffered staging + DIPTYCH load balance.
// Block = 4 waves; one wave-pair works q-chunk qcA=i, the other qcB=63-i
// (chunk roles flipped by blockIdx>>8 for SIMD balance across co-resident
// blocks). Shared key-prefix -> one staging stream of T=qcB+1 tiles; total
// compute per block = 130 wave-tiles = CONSTANT (zero tail imbalance).
// Ps uses stride-64 rows + XOR-16B-chunk swizzle (bank-conflict-free, as
// measured in round 3). grid 512 (bh in low 4 bits), block 256.
// ---------------------------------------------------------------------------
__global__ __launch_bounds__(256)
void attn_mfma(const unsigned short* __restrict__ ws, float* __restrict__ out) {
    const int bh   = blockIdx.x & 15;
    const int ip   = blockIdx.x >> 4;           // 0..31
    const int tid  = threadIdx.x;
    const int w    = tid >> 6, l = tid & 63;
    const int quad = l >> 4,  r16 = l & 15;

    const int qcA  = ip, qcB = 63 - ip;
    const int hvy  = (w >> 1) ^ (blockIdx.x >> 8);   // this wave-pair's chunk role
    const int myqc = hvy ? qcB : qcA;
    const int qoff = (w & 1) * 32;
    const int qlo  = myqc*64 + qoff;
    const int T    = qcB + 1;                   // tiles to stage

    const unsigned short* Qg  = ws;             // pre-scaled by log2e/sqrt(512)
    const unsigned short* Kg  = ws + (size_t)MSD;
    const unsigned short* Vtg = ws + 2*(size_t)MSD;

    __shared__ __align__(16) unsigned short Ks[2][64*64];
    __shared__ __align__(16) unsigned short Vs[2][64*64];
    __shared__ __align__(16) unsigned short Ps[4][32*64];
    unsigned short* PsW = Ps[w];

    const size_t kbase = (size_t)bh*SS*HD;
    const size_t vbase = (size_t)bh*HD*SS;

    // Q B-frags: lane holds Q[q = qlo+nt*16+r16][d = kc*32+quad*8+j]
    bf16x8 bqf[2][2];
    #pragma unroll
    for (int nt = 0; nt < 2; ++nt)
        #pragma unroll
        for (int kc = 0; kc < 2; ++kc)
            bqf[nt][kc] = *(const bf16x8*)&Qg[kbase + (size_t)(qlo + nt*16 + r16)*HD + kc*32 + quad*8];

    f32x4 od[4][2];   // O^T accum: [mt -> d][nt -> q]
    #pragma unroll
    for (int mt = 0; mt < 4; ++mt)
        #pragma unroll
        for (int nt = 0; nt < 2; ++nt) od[mt][nt] = (f32x4){0.f,0.f,0.f,0.f};
    float lsum[2] = {0.f, 0.f};

    // staging: wave w stages rows [w*16, w*16+16) of K and V^T (XOR-swizzled)
    const int sr8 = l >> 3, sc = l & 7;

    // prologue: stage tile 0 into buf 0
    #pragma unroll
    for (int u = 0; u < 2; ++u) {
        const int row = w*16 + u*8 + sr8;
        const int c   = sc ^ (row & 7);
        GLD16(&Kg [kbase + (size_t)row*HD + c*8], &Ks[0][(w*16 + u*8)*64]);
        GLD16(&Vtg[vbase + (size_t)row*SS + c*8], &Vs[0][(w*16 + u*8)*64]);
    }

    for (int t = 0; t < T; ++t) {
        __syncthreads();                        // drains DMA(t) for all waves

        if (t + 1 < T) {                        // issue DMA(t+1) into other buf
            const int jb1 = (t + 1)*64;
            const int b1  = (t + 1) & 1;
            #pragma unroll
            for (int u = 0; u < 2; ++u) {
                const int row = w*16 + u*8 + sr8;
                const int c   = sc ^ (row & 7);
                GLD16(&Kg [kbase + (size_t)(jb1 + row)*HD + c*8], &Ks[b1][(w*16 + u*8)*64]);
                GLD16(&Vtg[vbase + (size_t)row*SS + jb1 + c*8],   &Vs[b1][(w*16 + u*8)*64]);
            }
        }

        if (t <= myqc) {
            const unsigned short* Kb = Ks[t & 1];
            const unsigned short* Vb = Vs[t & 1];

            // ---- S^T = K Q^T : lane holds S^T[key = mt*16+quad*4+reg][q = nt*16+r16]
            f32x4 z[4][2];
            #pragma unroll
            for (int mt = 0; mt < 4; ++mt) {
                const int row = mt*16 + r16;
                bf16x8 ak0 = *(const bf16x8*)&Kb[row*64 + ((quad     ^ (row&7))*8)];
                bf16x8 ak1 = *(const bf16x8*)&Kb[row*64 + (((4+quad) ^ (row&7))*8)];
                #pragma unroll
                for (int nt = 0; nt < 2; ++nt) {
                    z[mt][nt] = __builtin_amdgcn_mfma_f32_16x16x32_bf16(ak0, bqf[nt][0],
                                    (f32x4){0.f,0.f,0.f,0.f}, 0, 0, 0);
                    z[mt][nt] = __builtin_amdgcn_mfma_f32_16x16x32_bf16(ak1, bqf[nt][1], z[mt][nt], 0, 0, 0);
                }
            }

            if (t == myqc) {   // causal mask on the diagonal tile
                #pragma unroll
                for (int mt = 0; mt < 4; ++mt)
                    #pragma unroll
                    for (int nt = 0; nt < 2; ++nt)
                        #pragma unroll
                        for (int reg = 0; reg < 4; ++reg)
                            if (mt*16 + quad*4 + reg > qoff + nt*16 + r16)
                                z[mt][nt][reg] = -1e30f;
            }

            // ---- P = exp2(z); accumulate l; packed b64 stores into wave-private Ps
            // write chunk c = 2mt+(quad>>1), sub (quad&1)*4, XOR row&7 swizzle
            #pragma unroll
            for (int mt = 0; mt < 4; ++mt)
                #pragma unroll
                for (int nt = 0; nt < 2; ++nt) {
                    #pragma unroll
                    for (int reg = 0; reg < 4; ++reg) {
                        z[mt][nt][reg] = exp2f(z[mt][nt][reg]);
                        lsum[nt] += z[mt][nt][reg];
                    }
                    uint2 pk;
                    pk.x = pk2bf(z[mt][nt][0], z[mt][nt][1]);
                    pk.y = pk2bf(z[mt][nt][2], z[mt][nt][3]);
                    const int prow = nt*16 + r16;
                    *(uint2*)&PsW[prow*64 + (((2*mt + (quad>>1)) ^ (prow&7))*8) + (quad&1)*4] = pk;
                }

            asm volatile("s_waitcnt lgkmcnt(0)" ::: "memory");  // wave-private round-trip

            // ---- O^T += V^T P^T  (read chunk c = 4kc+quad, XOR row&7)
            bf16x8 pf[2][2];
            #pragma unroll
            for (int nt = 0; nt < 2; ++nt) {
                const int prow = nt*16 + r16;
                #pragma unroll
                for (int kc = 0; kc < 2; ++kc)
                    pf[nt][kc] = *(const bf16x8*)&PsW[prow*64 + (((4*kc + quad) ^ (prow&7))*8)];
            }

            #pragma unroll
            for (int mt = 0; mt < 4; ++mt) {
                const int row = mt*16 + r16;
                bf16x8 av0 = *(const bf16x8*)&Vb[row*64 + ((quad     ^ (row&7))*8)];
                bf16x8 av1 = *(const bf16x8*)&Vb[row*64 + (((4+quad) ^ (row&7))*8)];
                #pragma unroll
                for (int nt = 0; nt < 2; ++nt) {
                    od[mt][nt] = __builtin_amdgcn_mfma_f32_16x16x32_bf16(av0, pf[nt][0], od[mt][nt], 0, 0, 0);
                    od[mt][nt] = __builtin_amdgcn_mfma_f32_16x16x32_bf16(av1, pf[nt][1], od[mt][nt], 0, 0, 0);
                }
            }
        }
    }

    // ---- l: sum the 4 quad-partials per q
    #pragma unroll
    for (int nt = 0; nt < 2; ++nt) {
        lsum[nt] += __shfl_xor(lsum[nt], 16);
        lsum[nt] += __shfl_xor(lsum[nt], 32);
    }

    const int b_ = bh >> 3, h = bh & 7;
    #pragma unroll
    for (int nt = 0; nt < 2; ++nt) {
        const float inv = 1.0f / lsum[nt];
        const int q = qlo + nt*16 + r16;
        float* op = out + ((size_t)(b_*SS + q))*DD + h*HD;
        #pragma unroll
        for (int mt = 0; mt < 4; ++mt) {
            float4 tt;
            tt.x = od[mt][nt][0]*inv; tt.y = od[mt][nt][1]*inv;
            tt.z = od[mt][nt][2]*inv; tt.w = od[mt][nt][3]*inv;
            *(float4*)&op[mt*16 + quad*4] = tt;
        }
    }
}

extern "C" void kernel_launch(void* const* d_in, const int* in_sizes, int n_in,
                              void* d_out, int out_size, void* d_ws, size_t ws_size,
                              hipStream_t stream) {
    const float* x  = (const float*)d_in[0];
    const float* Wq = (const float*)d_in[1];
    const float* bq = (const float*)d_in[2];
    const float* Wk = (const float*)d_in[3];
    const float* bk = (const float*)d_in[4];
    const float* Wv = (const float*)d_in[5];
    const float* bv = (const float*)d_in[6];
    float* out = (float*)d_out;
    unsigned short* ws = (unsigned short*)d_ws;

    const int nconv = (MSD/8 + 3*WSZ/8 + 255) / 256;
    convert_bf16<<<nconv, 256, 0, stream>>>(x, Wq, Wk, Wv, ws);

    dim3 ggrid(DD/128, (BB*SS)/128, 3);           // (4, 64, 3)
    qkv_mfma<<<ggrid, 256, 0, stream>>>(bq, bk, bv, ws);

    attn_mfma<<<512, 256, 0, stream>>>(ws, out);
}